// Round 6
// baseline (2663.853 us; speedup 1.0000x reference)
//
#include <hip/hip_runtime.h>
#include <math.h>

#define BT 256   // 4 waves per block

// ---------------------------------------------------------------------------
// Setup: transpose W1 and Wv1 into workspace as Wt[k][j] (k-major, 64 j's
// contiguous) so GEMM lanes can read w[j..j+7][k] as two float4's.
// ---------------------------------------------------------------------------
__global__ void transpose_weights(const float* __restrict__ W1,
                                  const float* __restrict__ Wv1,
                                  float* __restrict__ wt)
{
    int idx = blockIdx.x * 256 + threadIdx.x;
    if (idx < 64 * 256) {
        int j = idx >> 8, k = idx & 255;
        wt[k * 64 + j]         = W1[idx];
        wt[16384 + k * 64 + j] = Wv1[idx];
    }
}

// ---------------------------------------------------------------------------
// Fused main kernel. Even blocks = SNN/actor, odd blocks = critic.
// Each wave: one 64-row chunk. GEMM: lane (rg=lane>>3, jg=lane&7) owns an
// 8x8 register tile (rows rg*8+i, cols jg*8+jj). Epilogue: 8-row batches
// through a per-wave LDS exchange, lane = feature.
// ---------------------------------------------------------------------------
__global__ __launch_bounds__(BT, 3)
void snn_main(const float* __restrict__ x,
              const float* __restrict__ wt_all,
              const float* __restrict__ b1, const float* __restrict__ W2,
              const float* __restrict__ b2, const float* __restrict__ Wo,
              const float* __restrict__ bo,
              const float* __restrict__ beta_in, const float* __restrict__ thr_in,
              const float* __restrict__ beta_out,
              const float* __restrict__ bv1, const float* __restrict__ Wv2,
              const float* __restrict__ bv2,
              float* __restrict__ out, int B)
{
    __shared__ float Wsm0[4096];
    __shared__ float Wsm1[4096];
    __shared__ float exch[4][8][68];   // per-wave exchange, 68-pad: 2-way banks

    const int tid  = threadIdx.x;
    const int role = (int)blockIdx.x & 1;        // 0 = SNN, 1 = critic
    const int idx  = (int)blockIdx.x >> 1;

    // Stage small weights blocked: Wsm[(i>>2)*256 + j*4 + (i&3)] = W[j][i]
    if (role == 0) {
        for (int t = tid; t < 4096; t += BT) {
            int j = t >> 6, i = t & 63;
            int p = (i >> 2) * 256 + (j << 2) + (i & 3);
            Wsm0[p] = W2[t];
            Wsm1[p] = Wo[t];
        }
    } else {
        for (int t = tid; t < 4096; t += BT) {
            int j = t >> 6, i = t & 63;
            Wsm0[(i >> 2) * 256 + (j << 2) + (i & 3)] = Wv2[t];
        }
    }
    __syncthreads();

    const int lane = tid & 63;
    const int w    = __builtin_amdgcn_readfirstlane(tid >> 6);
    const int rg   = lane >> 3;
    const int jg   = lane & 7;

    const int  chunk = idx * 4 + w;
    const long row0  = (long)chunk * 64;
    if (row0 >= B) return;

    const float* wt   = wt_all + (role ? 16384 : 0);
    const float* wrow = wt + jg * 8;

    // ---- register-tiled GEMM: acc[i][jj] = sum_k x[row][k] * W[col][k] ----
    // Base pointer for this lane's 8 rows (rows rg*8 .. rg*8+7 of the chunk);
    // B % 64 == 0 for the bench shape, tail handled at the store.
    const float* xbase = x + (size_t)(row0 + rg * 8) * 256;

    float acc[8][8];
#pragma unroll
    for (int i = 0; i < 8; ++i)
#pragma unroll
        for (int j = 0; j < 8; ++j) acc[i][j] = 0.f;

    for (int kb = 0; kb < 64; ++kb) {
        float4 xq[8];
#pragma unroll
        for (int i = 0; i < 8; ++i)
            xq[i] = *(const float4*)(xbase + (size_t)i * 256 + kb * 4);
#pragma unroll
        for (int kk = 0; kk < 4; ++kk) {
            const float4 wa = *(const float4*)(wrow + (kb * 4 + kk) * 64);
            const float4 wb = *(const float4*)(wrow + (kb * 4 + kk) * 64 + 4);
#pragma unroll
            for (int i = 0; i < 8; ++i) {
                const float xs = (kk == 0) ? xq[i].x : (kk == 1) ? xq[i].y
                               : (kk == 2) ? xq[i].z : xq[i].w;
                acc[i][0] = fmaf(xs, wa.x, acc[i][0]);
                acc[i][1] = fmaf(xs, wa.y, acc[i][1]);
                acc[i][2] = fmaf(xs, wa.z, acc[i][2]);
                acc[i][3] = fmaf(xs, wa.w, acc[i][3]);
                acc[i][4] = fmaf(xs, wb.x, acc[i][4]);
                acc[i][5] = fmaf(xs, wb.y, acc[i][5]);
                acc[i][6] = fmaf(xs, wb.z, acc[i][6]);
                acc[i][7] = fmaf(xs, wb.w, acc[i][7]);
            }
        }
    }

    float* ex = &exch[w][0][0];   // [8][68]

    if (role == 0) {
        // ------------------------- SNN / actor -------------------------
        const float b1r   = b1[lane], b2r = b2[lane], bor = bo[lane];
        const float betac = fminf(fmaxf(beta_in[lane], 0.f), 1.f);
        const float thr   = thr_in[lane];
        const float betao = fminf(fmaxf(beta_out[0], 0.f), 1.f);

        for (int b = 0; b < 8; ++b) {
            if (rg == b) {
#pragma unroll
                for (int i = 0; i < 8; ++i) {
                    *(float4*)&ex[i * 68 + jg * 8] =
                        make_float4(acc[i][0], acc[i][1], acc[i][2], acc[i][3]);
                    *(float4*)&ex[i * 68 + jg * 8 + 4] =
                        make_float4(acc[i][4], acc[i][5], acc[i][6], acc[i][7]);
                }
            }
            asm volatile("s_waitcnt lgkmcnt(0)" ::: "memory");

            // c1 -> 10 LIF steps (only mem1 recurs; mem2/mem3 carries are dead
            // in the reference step fn, so W2/Wo run once at t=9)
            float m1[8];
#pragma unroll
            for (int r = 0; r < 8; ++r) {
                const float c1 = ex[r * 68 + lane] + b1r;
                float m = 0.f;
#pragma unroll
                for (int t = 0; t < 10; ++t) {
                    const float rst = ((m - thr) > 0.f) ? thr : 0.f;  // OLD mem
                    m = fmaf(betac, m, c1) - rst;
                }
                m1[r] = m;
            }
            asm volatile("s_waitcnt lgkmcnt(0)" ::: "memory");
            // spikes as 0/1 floats into the exchange (own slot only)
#pragma unroll
            for (int r = 0; r < 8; ++r)
                ex[r * 68 + lane] = ((m1[r] - thr) > 0.f) ? 1.f : 0.f;
            asm volatile("s_waitcnt lgkmcnt(0)" ::: "memory");

            // c2 = spk1 @ W2^T + b2  (pure fmaf; fma(w,0,c)=c, fma(w,1,c)=w+c)
            float c2[8];
#pragma unroll
            for (int r = 0; r < 8; ++r) c2[r] = b2r;
#pragma unroll
            for (int ib = 0; ib < 16; ++ib) {
                const float4 wv = *(const float4*)&Wsm0[ib * 256 + lane * 4];
#pragma unroll
                for (int r = 0; r < 8; ++r) {
                    const float4 s4 = *(const float4*)&ex[r * 68 + ib * 4];
                    c2[r] = fmaf(wv.x, s4.x, c2[r]);
                    c2[r] = fmaf(wv.y, s4.y, c2[r]);
                    c2[r] = fmaf(wv.z, s4.z, c2[r]);
                    c2[r] = fmaf(wv.w, s4.w, c2[r]);
                }
            }
            float m2[8];
#pragma unroll
            for (int r = 0; r < 8; ++r) {
                const float rst2 = ((m1[r] - thr) > 0.f) ? thr : 0.f;  // NEW mem1 (ref bug kept)
                m2[r] = fmaf(betac, m1[r], c2[r]) - rst2;
            }
            asm volatile("s_waitcnt lgkmcnt(0)" ::: "memory");
#pragma unroll
            for (int r = 0; r < 8; ++r)
                ex[r * 68 + lane] = ((m2[r] - thr) > 0.f) ? 1.f : 0.f;
            asm volatile("s_waitcnt lgkmcnt(0)" ::: "memory");

            // c3 = spk2 @ Wo^T + bo
            float c3[8];
#pragma unroll
            for (int r = 0; r < 8; ++r) c3[r] = bor;
#pragma unroll
            for (int ib = 0; ib < 16; ++ib) {
                const float4 wv = *(const float4*)&Wsm1[ib * 256 + lane * 4];
#pragma unroll
                for (int r = 0; r < 8; ++r) {
                    const float4 s4 = *(const float4*)&ex[r * 68 + ib * 4];
                    c3[r] = fmaf(wv.x, s4.x, c3[r]);
                    c3[r] = fmaf(wv.y, s4.y, c3[r]);
                    c3[r] = fmaf(wv.z, s4.z, c3[r]);
                    c3[r] = fmaf(wv.w, s4.w, c3[r]);
                }
            }
            const long rowb = row0 + (long)b * 8;
#pragma unroll
            for (int r = 0; r < 8; ++r) {
                const long rr = rowb + r;
                if (rr < B) {
                    const float m3 = fmaf(betao, m2[r], c3[r]);  // lif_none on NEW mem2
                    out[(size_t)rr * 64 + lane] = tanhf(m3) * 3.14159265358979323846f;
                }
            }
            asm volatile("s_waitcnt lgkmcnt(0)" ::: "memory");
        }
    } else {
        // --------------------------- critic ---------------------------
        const float bv1r = bv1[lane], bv2r = bv2[lane];
        float* outc = out + (size_t)B * 64;

        for (int b = 0; b < 8; ++b) {
            if (rg == b) {
#pragma unroll
                for (int i = 0; i < 8; ++i) {
                    *(float4*)&ex[i * 68 + jg * 8] =
                        make_float4(acc[i][0], acc[i][1], acc[i][2], acc[i][3]);
                    *(float4*)&ex[i * 68 + jg * 8 + 4] =
                        make_float4(acc[i][4], acc[i][5], acc[i][6], acc[i][7]);
                }
            }
            asm volatile("s_waitcnt lgkmcnt(0)" ::: "memory");

            float hreg[8];
#pragma unroll
            for (int r = 0; r < 8; ++r)
                hreg[r] = fmaxf(ex[r * 68 + lane] + bv1r, 0.f);
            asm volatile("s_waitcnt lgkmcnt(0)" ::: "memory");
#pragma unroll
            for (int r = 0; r < 8; ++r)
                ex[r * 68 + lane] = hreg[r];
            asm volatile("s_waitcnt lgkmcnt(0)" ::: "memory");

            float cv[8];
#pragma unroll
            for (int r = 0; r < 8; ++r) cv[r] = bv2r;
#pragma unroll
            for (int ib = 0; ib < 16; ++ib) {
                const float4 wv = *(const float4*)&Wsm0[ib * 256 + lane * 4];
#pragma unroll
                for (int r = 0; r < 8; ++r) {
                    const float4 h4 = *(const float4*)&ex[r * 68 + ib * 4];
                    cv[r] = fmaf(wv.x, h4.x, cv[r]);
                    cv[r] = fmaf(wv.y, h4.y, cv[r]);
                    cv[r] = fmaf(wv.z, h4.z, cv[r]);
                    cv[r] = fmaf(wv.w, h4.w, cv[r]);
                }
            }
            const long rowb = row0 + (long)b * 8;
#pragma unroll
            for (int r = 0; r < 8; ++r) {
                const long rr = rowb + r;
                if (rr < B)
                    outc[(size_t)rr * 64 + lane] = fmaxf(cv[r], 0.f);
            }
            asm volatile("s_waitcnt lgkmcnt(0)" ::: "memory");
        }
    }
}

extern "C" void kernel_launch(void* const* d_in, const int* in_sizes, int n_in,
                              void* d_out, int out_size, void* d_ws, size_t ws_size,
                              hipStream_t stream)
{
    const float* x        = (const float*)d_in[0];
    const float* W1       = (const float*)d_in[1];
    const float* b1       = (const float*)d_in[2];
    const float* W2       = (const float*)d_in[3];
    const float* b2       = (const float*)d_in[4];
    const float* Wo       = (const float*)d_in[5];
    const float* bo       = (const float*)d_in[6];
    const float* beta_in  = (const float*)d_in[7];
    const float* thr_in   = (const float*)d_in[8];
    const float* beta_out = (const float*)d_in[9];
    const float* Wv1      = (const float*)d_in[10];
    const float* bv1      = (const float*)d_in[11];
    const float* Wv2      = (const float*)d_in[12];
    const float* bv2      = (const float*)d_in[13];
    float* out = (float*)d_out;
    float* wt  = (float*)d_ws;          // 32768 floats = 128 KB

    const int B = in_sizes[0] / 256;

    hipLaunchKernelGGL(transpose_weights, dim3(64), dim3(256), 0, stream,
                       W1, Wv1, wt);

    const int chunks = (B + 63) / 64;           // 2048 for B=131072
    const int bpr    = (chunks + 3) / 4;        // blocks per role (4 waves each)
    hipLaunchKernelGGL(snn_main, dim3(2 * bpr), dim3(BT), 0, stream,
                       x, wt, b1, W2, b2, Wo, bo, beta_in, thr_in, beta_out,
                       bv1, Wv2, bv2, out, B);
}

// Round 7
// 1179.683 us; speedup vs baseline: 2.2581x; 2.2581x over previous
//
#include <hip/hip_runtime.h>
#include <math.h>

#define BT 256   // 4 waves per block

// ---------------------------------------------------------------------------
// Workspace layout (floats):
//   [0,     16384): W1t  k-major:  wt[k*64 + j] = W1[j][k]
//   [16384, 32768): Wv1t k-major
//   [32768, 36864): W2b  blocked: [(i>>2)*256 + j*4 + (i&3)] = W2[j][i]
//   [36864, 40960): Wob  blocked
//   [40960, 45056): Wv2b blocked
// ---------------------------------------------------------------------------
__global__ void prep_weights(const float* __restrict__ W1,
                             const float* __restrict__ Wv1,
                             const float* __restrict__ W2,
                             const float* __restrict__ Wo,
                             const float* __restrict__ Wv2,
                             float* __restrict__ ws)
{
    int idx = blockIdx.x * 256 + threadIdx.x;
    if (idx < 16384) {
        int j = idx >> 8, k = idx & 255;
        ws[k * 64 + j]         = W1[idx];
        ws[16384 + k * 64 + j] = Wv1[idx];
    }
    if (idx < 4096) {
        int j = idx >> 6, i = idx & 63;
        int p = (i >> 2) * 256 + (j << 2) + (i & 3);
        ws[32768 + p] = W2[idx];
        ws[36864 + p] = Wo[idx];
        ws[40960 + p] = Wv2[idx];
    }
}

// ---------------------------------------------------------------------------
// One block = 64 rows. Waves 0,1 = SNN/actor halves; waves 2,3 = critic
// halves (same rows -> x HBM-fetched once per block). Each wave: 32 rows x
// 64 cols GEMM, lane (rg=lane>>3, jg=lane&7) owns a 4x8 register tile.
// No block-level barriers; per-wave LDS exchange only (wave-lockstep +
// lgkmcnt waits). Small matvec weights read coalesced from ws (L1/L2).
// ---------------------------------------------------------------------------
__global__ __launch_bounds__(BT)
void snn_main(const float* __restrict__ x,
              const float* __restrict__ ws,
              const float* __restrict__ b1, const float* __restrict__ b2,
              const float* __restrict__ bo,
              const float* __restrict__ beta_in, const float* __restrict__ thr_in,
              const float* __restrict__ beta_out,
              const float* __restrict__ bv1, const float* __restrict__ bv2,
              float* __restrict__ out, int B)
{
    __shared__ float exch[4][8][68];   // per-wave 8-row exchange, 68-pad

    const int tid  = threadIdx.x;
    const int lane = tid & 63;
    const int w    = __builtin_amdgcn_readfirstlane(tid >> 6);  // 0..3
    const int role = w >> 1;           // 0 = SNN, 1 = critic
    const int half = w & 1;            // which 32-row half of the block
    const int rg   = lane >> 3;        // row group (4 rows)
    const int jg   = lane & 7;         // col group (8 cols)

    const long row0 = (long)blockIdx.x * 64 + half * 32;
    if (row0 >= B) return;             // safe: no block barriers below

    const float* wrow = ws + (role ? 16384 : 0) + jg * 8;

    // Per-row pointers (clamped for tails); bumped 16 B per kb step.
    const float* xp0;
    const float* xp1;
    const float* xp2;
    const float* xp3;
    {
        long r0 = row0 + rg * 4;
        long r1 = r0 + 1, r2 = r0 + 2, r3 = r0 + 3;
        if (r1 >= B) r1 = B - 1;
        if (r2 >= B) r2 = B - 1;
        if (r3 >= B) r3 = B - 1;
        xp0 = x + (size_t)r0 * 256;
        xp1 = x + (size_t)r1 * 256;
        xp2 = x + (size_t)r2 * 256;
        xp3 = x + (size_t)r3 * 256;
    }

    // ---- register-tiled GEMM: acc[i][jj] = sum_k x[row][k] * W[col][k] ----
    float acc[4][8];
#pragma unroll
    for (int i = 0; i < 4; ++i)
#pragma unroll
        for (int j = 0; j < 8; ++j) acc[i][j] = 0.f;

    for (int kb = 0; kb < 64; ++kb) {
        const float4 xq0 = *(const float4*)(xp0 + kb * 4);
        const float4 xq1 = *(const float4*)(xp1 + kb * 4);
        const float4 xq2 = *(const float4*)(xp2 + kb * 4);
        const float4 xq3 = *(const float4*)(xp3 + kb * 4);
#pragma unroll
        for (int kk = 0; kk < 4; ++kk) {
            const float4 wa = *(const float4*)(wrow + (kb * 4 + kk) * 64);
            const float4 wb = *(const float4*)(wrow + (kb * 4 + kk) * 64 + 4);
            const float x0 = (kk == 0) ? xq0.x : (kk == 1) ? xq0.y : (kk == 2) ? xq0.z : xq0.w;
            const float x1 = (kk == 0) ? xq1.x : (kk == 1) ? xq1.y : (kk == 2) ? xq1.z : xq1.w;
            const float x2 = (kk == 0) ? xq2.x : (kk == 1) ? xq2.y : (kk == 2) ? xq2.z : xq2.w;
            const float x3 = (kk == 0) ? xq3.x : (kk == 1) ? xq3.y : (kk == 2) ? xq3.z : xq3.w;
            acc[0][0] = fmaf(x0, wa.x, acc[0][0]); acc[0][1] = fmaf(x0, wa.y, acc[0][1]);
            acc[0][2] = fmaf(x0, wa.z, acc[0][2]); acc[0][3] = fmaf(x0, wa.w, acc[0][3]);
            acc[0][4] = fmaf(x0, wb.x, acc[0][4]); acc[0][5] = fmaf(x0, wb.y, acc[0][5]);
            acc[0][6] = fmaf(x0, wb.z, acc[0][6]); acc[0][7] = fmaf(x0, wb.w, acc[0][7]);
            acc[1][0] = fmaf(x1, wa.x, acc[1][0]); acc[1][1] = fmaf(x1, wa.y, acc[1][1]);
            acc[1][2] = fmaf(x1, wa.z, acc[1][2]); acc[1][3] = fmaf(x1, wa.w, acc[1][3]);
            acc[1][4] = fmaf(x1, wb.x, acc[1][4]); acc[1][5] = fmaf(x1, wb.y, acc[1][5]);
            acc[1][6] = fmaf(x1, wb.z, acc[1][6]); acc[1][7] = fmaf(x1, wb.w, acc[1][7]);
            acc[2][0] = fmaf(x2, wa.x, acc[2][0]); acc[2][1] = fmaf(x2, wa.y, acc[2][1]);
            acc[2][2] = fmaf(x2, wa.z, acc[2][2]); acc[2][3] = fmaf(x2, wa.w, acc[2][3]);
            acc[2][4] = fmaf(x2, wb.x, acc[2][4]); acc[2][5] = fmaf(x2, wb.y, acc[2][5]);
            acc[2][6] = fmaf(x2, wb.z, acc[2][6]); acc[2][7] = fmaf(x2, wb.w, acc[2][7]);
            acc[3][0] = fmaf(x3, wa.x, acc[3][0]); acc[3][1] = fmaf(x3, wa.y, acc[3][1]);
            acc[3][2] = fmaf(x3, wa.z, acc[3][2]); acc[3][3] = fmaf(x3, wa.w, acc[3][3]);
            acc[3][4] = fmaf(x3, wb.x, acc[3][4]); acc[3][5] = fmaf(x3, wb.y, acc[3][5]);
            acc[3][6] = fmaf(x3, wb.z, acc[3][6]); acc[3][7] = fmaf(x3, wb.w, acc[3][7]);
        }
    }

    float* ex = &exch[w][0][0];        // [8][68]

    if (role == 0) {
        // ------------------------- SNN / actor -------------------------
        const float b1r   = b1[lane], b2r = b2[lane], bor = bo[lane];
        const float betac = fminf(fmaxf(beta_in[lane], 0.f), 1.f);
        const float thr   = thr_in[lane];
        const float betao = fminf(fmaxf(beta_out[0], 0.f), 1.f);
        const float* W2b  = ws + 32768;
        const float* Wob  = ws + 36864;

        for (int b = 0; b < 4; ++b) {   // 4 batches of 8 rows (local rows b*8..)
            if ((rg >> 1) == b) {
                const int r0 = (rg & 1) * 4;
#pragma unroll
                for (int i = 0; i < 4; ++i) {
                    *(float4*)&ex[(r0 + i) * 68 + jg * 8] =
                        make_float4(acc[i][0], acc[i][1], acc[i][2], acc[i][3]);
                    *(float4*)&ex[(r0 + i) * 68 + jg * 8 + 4] =
                        make_float4(acc[i][4], acc[i][5], acc[i][6], acc[i][7]);
                }
            }
            asm volatile("s_waitcnt lgkmcnt(0)" ::: "memory");

            // 10 LIF steps (only mem1 recurs; carried mem2/mem3 are dead in
            // the reference step fn, so W2/Wo run once at the final step)
            float m1[8];
#pragma unroll
            for (int r = 0; r < 8; ++r) {
                const float c1 = ex[r * 68 + lane] + b1r;
                float m = 0.f;
#pragma unroll
                for (int t = 0; t < 10; ++t) {
                    const float rst = ((m - thr) > 0.f) ? thr : 0.f;  // OLD mem
                    m = fmaf(betac, m, c1) - rst;
                }
                m1[r] = m;
            }
            asm volatile("s_waitcnt lgkmcnt(0)" ::: "memory");
#pragma unroll
            for (int r = 0; r < 8; ++r)   // spk1 as 0/1 floats, own column
                ex[r * 68 + lane] = ((m1[r] - thr) > 0.f) ? 1.f : 0.f;
            asm volatile("s_waitcnt lgkmcnt(0)" ::: "memory");

            // c2 = spk1 @ W2^T + b2 (coalesced global weight loads)
            float c2[8];
#pragma unroll
            for (int r = 0; r < 8; ++r) c2[r] = b2r;
#pragma unroll
            for (int ib = 0; ib < 16; ++ib) {
                const float4 wv = *(const float4*)&W2b[ib * 256 + lane * 4];
#pragma unroll
                for (int r = 0; r < 8; ++r) {
                    const float4 s4 = *(const float4*)&ex[r * 68 + ib * 4];
                    c2[r] = fmaf(wv.x, s4.x, c2[r]);
                    c2[r] = fmaf(wv.y, s4.y, c2[r]);
                    c2[r] = fmaf(wv.z, s4.z, c2[r]);
                    c2[r] = fmaf(wv.w, s4.w, c2[r]);
                }
            }
            float m2[8];
#pragma unroll
            for (int r = 0; r < 8; ++r) {
                const float rst2 = ((m1[r] - thr) > 0.f) ? thr : 0.f; // NEW mem1 (ref bug kept)
                m2[r] = fmaf(betac, m1[r], c2[r]) - rst2;
            }
            asm volatile("s_waitcnt lgkmcnt(0)" ::: "memory");
#pragma unroll
            for (int r = 0; r < 8; ++r)
                ex[r * 68 + lane] = ((m2[r] - thr) > 0.f) ? 1.f : 0.f;
            asm volatile("s_waitcnt lgkmcnt(0)" ::: "memory");

            // c3 = spk2 @ Wo^T + bo
            float c3[8];
#pragma unroll
            for (int r = 0; r < 8; ++r) c3[r] = bor;
#pragma unroll
            for (int ib = 0; ib < 16; ++ib) {
                const float4 wv = *(const float4*)&Wob[ib * 256 + lane * 4];
#pragma unroll
                for (int r = 0; r < 8; ++r) {
                    const float4 s4 = *(const float4*)&ex[r * 68 + ib * 4];
                    c3[r] = fmaf(wv.x, s4.x, c3[r]);
                    c3[r] = fmaf(wv.y, s4.y, c3[r]);
                    c3[r] = fmaf(wv.z, s4.z, c3[r]);
                    c3[r] = fmaf(wv.w, s4.w, c3[r]);
                }
            }
            const long rowb = row0 + (long)b * 8;
#pragma unroll
            for (int r = 0; r < 8; ++r) {
                const long rr = rowb + r;
                if (rr < B) {
                    const float m3 = fmaf(betao, m2[r], c3[r]);   // lif_none on NEW mem2
                    out[(size_t)rr * 64 + lane] = tanhf(m3) * 3.14159265358979323846f;
                }
            }
            asm volatile("s_waitcnt lgkmcnt(0)" ::: "memory");
        }
    } else {
        // --------------------------- critic ---------------------------
        const float bv1r = bv1[lane], bv2r = bv2[lane];
        const float* Wv2b = ws + 40960;
        float* outc = out + (size_t)B * 64;

        for (int b = 0; b < 4; ++b) {
            if ((rg >> 1) == b) {
                const int r0 = (rg & 1) * 4;
#pragma unroll
                for (int i = 0; i < 4; ++i) {
                    *(float4*)&ex[(r0 + i) * 68 + jg * 8] =
                        make_float4(acc[i][0], acc[i][1], acc[i][2], acc[i][3]);
                    *(float4*)&ex[(r0 + i) * 68 + jg * 8 + 4] =
                        make_float4(acc[i][4], acc[i][5], acc[i][6], acc[i][7]);
                }
            }
            asm volatile("s_waitcnt lgkmcnt(0)" ::: "memory");

            float hreg[8];
#pragma unroll
            for (int r = 0; r < 8; ++r)
                hreg[r] = fmaxf(ex[r * 68 + lane] + bv1r, 0.f);
            asm volatile("s_waitcnt lgkmcnt(0)" ::: "memory");
#pragma unroll
            for (int r = 0; r < 8; ++r)
                ex[r * 68 + lane] = hreg[r];
            asm volatile("s_waitcnt lgkmcnt(0)" ::: "memory");

            float cv[8];
#pragma unroll
            for (int r = 0; r < 8; ++r) cv[r] = bv2r;
#pragma unroll
            for (int ib = 0; ib < 16; ++ib) {
                const float4 wv = *(const float4*)&Wv2b[ib * 256 + lane * 4];
#pragma unroll
                for (int r = 0; r < 8; ++r) {
                    const float4 h4 = *(const float4*)&ex[r * 68 + ib * 4];
                    cv[r] = fmaf(wv.x, h4.x, cv[r]);
                    cv[r] = fmaf(wv.y, h4.y, cv[r]);
                    cv[r] = fmaf(wv.z, h4.z, cv[r]);
                    cv[r] = fmaf(wv.w, h4.w, cv[r]);
                }
            }
            const long rowb = row0 + (long)b * 8;
#pragma unroll
            for (int r = 0; r < 8; ++r) {
                const long rr = rowb + r;
                if (rr < B)
                    outc[(size_t)rr * 64 + lane] = fmaxf(cv[r], 0.f);
            }
            asm volatile("s_waitcnt lgkmcnt(0)" ::: "memory");
        }
    }
}

extern "C" void kernel_launch(void* const* d_in, const int* in_sizes, int n_in,
                              void* d_out, int out_size, void* d_ws, size_t ws_size,
                              hipStream_t stream)
{
    const float* x        = (const float*)d_in[0];
    const float* W1       = (const float*)d_in[1];
    const float* b1       = (const float*)d_in[2];
    const float* W2       = (const float*)d_in[3];
    const float* b2       = (const float*)d_in[4];
    const float* Wo       = (const float*)d_in[5];
    const float* bo       = (const float*)d_in[6];
    const float* beta_in  = (const float*)d_in[7];
    const float* thr_in   = (const float*)d_in[8];
    const float* beta_out = (const float*)d_in[9];
    const float* Wv1      = (const float*)d_in[10];
    const float* bv1      = (const float*)d_in[11];
    const float* Wv2      = (const float*)d_in[12];
    const float* bv2      = (const float*)d_in[13];
    float* out = (float*)d_out;
    float* ws  = (float*)d_ws;          // needs 45056 floats = 176 KB

    const int B = in_sizes[0] / 256;

    hipLaunchKernelGGL(prep_weights, dim3(64), dim3(256), 0, stream,
                       W1, Wv1, W2, Wo, Wv2, ws);

    const int nblk = (B + 63) / 64;     // 2048 for B=131072
    hipLaunchKernelGGL(snn_main, dim3(nblk), dim3(BT), 0, stream,
                       x, ws, b1, b2, bo, beta_in, thr_in, beta_out,
                       bv1, bv2, out, B);
}

// Round 9
// 487.714 us; speedup vs baseline: 5.4619x; 2.4188x over previous
//
#include <hip/hip_runtime.h>
#include <math.h>

#define BT 256   // 4 waves per block

// ---------------------------------------------------------------------------
// Workspace layout (floats):
//   [0,     16384): W1t  k-major:  wt[k*64 + j] = W1[j][k]
//   [16384, 32768): Wv1t k-major
//   [32768, 36864): W2b  blocked: [(i>>2)*256 + j*4 + (i&3)] = W2[j][i]
//   [36864, 40960): Wob  blocked
//   [40960, 45056): Wv2b blocked
// ---------------------------------------------------------------------------
__global__ void prep_weights(const float* __restrict__ W1,
                             const float* __restrict__ Wv1,
                             const float* __restrict__ W2,
                             const float* __restrict__ Wo,
                             const float* __restrict__ Wv2,
                             float* __restrict__ ws)
{
    int idx = blockIdx.x * 256 + threadIdx.x;
    if (idx < 16384) {
        int j = idx >> 8, k = idx & 255;
        ws[k * 64 + j]         = W1[idx];
        ws[16384 + k * 64 + j] = Wv1[idx];
    }
    if (idx < 4096) {
        int j = idx >> 6, i = idx & 63;
        int p = (i >> 2) * 256 + (j << 2) + (i & 3);
        ws[32768 + p] = W2[idx];
        ws[36864 + p] = Wo[idx];
        ws[40960 + p] = Wv2[idx];
    }
}

// ---------------------------------------------------------------------------
// One block = 64 rows. Waves 0,1 = SNN/actor halves; waves 2,3 = critic
// halves (same rows -> x HBM/L3-fetched once per block). Each wave: 32x64
// register-tiled GEMM (lane rg=lane>>3, jg=lane&7 owns 4x8), then acc is
// dumped to per-wave LDS st[32][68] IMMEDIATELY (ends acc liveness -> no
// spill), and the epilogue re-reads it per 8-row batch. No block barriers;
// wave-lockstep + data deps + lgkmcnt waits only.
// ---------------------------------------------------------------------------
__global__ __launch_bounds__(BT)
void snn_main(const float* __restrict__ x,
              const float* __restrict__ ws,
              const float* __restrict__ b1, const float* __restrict__ b2,
              const float* __restrict__ bo,
              const float* __restrict__ beta_in, const float* __restrict__ thr_in,
              const float* __restrict__ beta_out,
              const float* __restrict__ bv1, const float* __restrict__ bv2,
              float* __restrict__ out, int B)
{
    __shared__ float st[4][32][68];    // per-wave 32-row tile, 68-pad (2 ln/bank)

    const int tid  = threadIdx.x;
    const int lane = tid & 63;
    const int w    = __builtin_amdgcn_readfirstlane(tid >> 6);  // 0..3
    const int role = w >> 1;           // 0 = SNN, 1 = critic
    const int half = w & 1;            // which 32-row half of the block
    const int rg   = lane >> 3;        // row group (4 rows)
    const int jg   = lane & 7;         // col group (8 cols)

    const long row0 = (long)blockIdx.x * 64 + half * 32;
    if (row0 >= B) return;             // safe: no block barriers below

    const float* wrow = ws + (role ? 16384 : 0) + jg * 8;

    const float* xp0;
    const float* xp1;
    const float* xp2;
    const float* xp3;
    {
        long r0 = row0 + rg * 4;
        long r1 = r0 + 1, r2 = r0 + 2, r3 = r0 + 3;
        if (r1 >= B) r1 = B - 1;
        if (r2 >= B) r2 = B - 1;
        if (r3 >= B) r3 = B - 1;
        xp0 = x + (size_t)r0 * 256;
        xp1 = x + (size_t)r1 * 256;
        xp2 = x + (size_t)r2 * 256;
        xp3 = x + (size_t)r3 * 256;
    }

    // ---- register-tiled GEMM: acc[i][jj] = sum_k x[row][k] * W[col][k] ----
    float acc[4][8];
#pragma unroll
    for (int i = 0; i < 4; ++i)
#pragma unroll
        for (int j = 0; j < 8; ++j) acc[i][j] = 0.f;

#pragma unroll 2
    for (int kb = 0; kb < 64; ++kb) {
        const float4 xq0 = *(const float4*)(xp0 + kb * 4);
        const float4 xq1 = *(const float4*)(xp1 + kb * 4);
        const float4 xq2 = *(const float4*)(xp2 + kb * 4);
        const float4 xq3 = *(const float4*)(xp3 + kb * 4);
#pragma unroll
        for (int kk = 0; kk < 4; ++kk) {
            const float4 wa = *(const float4*)(wrow + (kb * 4 + kk) * 64);
            const float4 wb = *(const float4*)(wrow + (kb * 4 + kk) * 64 + 4);
            const float x0 = (kk == 0) ? xq0.x : (kk == 1) ? xq0.y : (kk == 2) ? xq0.z : xq0.w;
            const float x1 = (kk == 0) ? xq1.x : (kk == 1) ? xq1.y : (kk == 2) ? xq1.z : xq1.w;
            const float x2 = (kk == 0) ? xq2.x : (kk == 1) ? xq2.y : (kk == 2) ? xq2.z : xq2.w;
            const float x3 = (kk == 0) ? xq3.x : (kk == 1) ? xq3.y : (kk == 2) ? xq3.z : xq3.w;
            acc[0][0] = fmaf(x0, wa.x, acc[0][0]); acc[0][1] = fmaf(x0, wa.y, acc[0][1]);
            acc[0][2] = fmaf(x0, wa.z, acc[0][2]); acc[0][3] = fmaf(x0, wa.w, acc[0][3]);
            acc[0][4] = fmaf(x0, wb.x, acc[0][4]); acc[0][5] = fmaf(x0, wb.y, acc[0][5]);
            acc[0][6] = fmaf(x0, wb.z, acc[0][6]); acc[0][7] = fmaf(x0, wb.w, acc[0][7]);
            acc[1][0] = fmaf(x1, wa.x, acc[1][0]); acc[1][1] = fmaf(x1, wa.y, acc[1][1]);
            acc[1][2] = fmaf(x1, wa.z, acc[1][2]); acc[1][3] = fmaf(x1, wa.w, acc[1][3]);
            acc[1][4] = fmaf(x1, wb.x, acc[1][4]); acc[1][5] = fmaf(x1, wb.y, acc[1][5]);
            acc[1][6] = fmaf(x1, wb.z, acc[1][6]); acc[1][7] = fmaf(x1, wb.w, acc[1][7]);
            acc[2][0] = fmaf(x2, wa.x, acc[2][0]); acc[2][1] = fmaf(x2, wa.y, acc[2][1]);
            acc[2][2] = fmaf(x2, wa.z, acc[2][2]); acc[2][3] = fmaf(x2, wa.w, acc[2][3]);
            acc[2][4] = fmaf(x2, wb.x, acc[2][4]); acc[2][5] = fmaf(x2, wb.y, acc[2][5]);
            acc[2][6] = fmaf(x2, wb.z, acc[2][6]); acc[2][7] = fmaf(x2, wb.w, acc[2][7]);
            acc[3][0] = fmaf(x3, wa.x, acc[3][0]); acc[3][1] = fmaf(x3, wa.y, acc[3][1]);
            acc[3][2] = fmaf(x3, wa.z, acc[3][2]); acc[3][3] = fmaf(x3, wa.w, acc[3][3]);
            acc[3][4] = fmaf(x3, wb.x, acc[3][4]); acc[3][5] = fmaf(x3, wb.y, acc[3][5]);
            acc[3][6] = fmaf(x3, wb.z, acc[3][6]); acc[3][7] = fmaf(x3, wb.w, acc[3][7]);
        }
    }

    // ---- dump the whole tile to LDS NOW: acc's live range ends here ----
    float* sw = &st[w][0][0];          // [32][68]
#pragma unroll
    for (int i = 0; i < 4; ++i) {
        *(float4*)&sw[(rg * 4 + i) * 68 + jg * 8] =
            make_float4(acc[i][0], acc[i][1], acc[i][2], acc[i][3]);
        *(float4*)&sw[(rg * 4 + i) * 68 + jg * 8 + 4] =
            make_float4(acc[i][4], acc[i][5], acc[i][6], acc[i][7]);
    }
    asm volatile("s_waitcnt lgkmcnt(0)" ::: "memory");

    if (role == 0) {
        // ------------------------- SNN / actor -------------------------
        const float b1r   = b1[lane], b2r = b2[lane], bor = bo[lane];
        const float betac = fminf(fmaxf(beta_in[lane], 0.f), 1.f);
        const float thr   = thr_in[lane];
        const float betao = fminf(fmaxf(beta_out[0], 0.f), 1.f);
        const float* W2b  = ws + 32768;
        const float* Wob  = ws + 36864;

        for (int b = 0; b < 4; ++b) {   // 8-row batches
            // 10 LIF steps (only mem1 recurs; carried mem2/mem3 are dead in
            // the reference step fn, so W2/Wo run once at the final step)
            float m1[8];
#pragma unroll
            for (int r = 0; r < 8; ++r) {
                const float c1 = sw[(b * 8 + r) * 68 + lane] + b1r;
                float m = 0.f;
#pragma unroll
                for (int t = 0; t < 10; ++t) {
                    const float rst = ((m - thr) > 0.f) ? thr : 0.f;  // OLD mem
                    m = fmaf(betac, m, c1) - rst;
                }
                m1[r] = m;
            }
            // spk1 as 0/1 floats overwrite c1 slots (RAW-safe: write data
            // depends on the read, so the read has completed)
#pragma unroll
            for (int r = 0; r < 8; ++r)
                sw[(b * 8 + r) * 68 + lane] = ((m1[r] - thr) > 0.f) ? 1.f : 0.f;
            asm volatile("s_waitcnt lgkmcnt(0)" ::: "memory");

            // c2 = spk1 @ W2^T + b2 (coalesced global weights, LDS broadcast)
            float c2[8];
#pragma unroll
            for (int r = 0; r < 8; ++r) c2[r] = b2r;
#pragma unroll 4
            for (int ib = 0; ib < 16; ++ib) {
                const float4 wv = *(const float4*)&W2b[ib * 256 + lane * 4];
#pragma unroll
                for (int r = 0; r < 8; ++r) {
                    const float4 s4 = *(const float4*)&sw[(b * 8 + r) * 68 + ib * 4];
                    c2[r] = fmaf(wv.x, s4.x, c2[r]);
                    c2[r] = fmaf(wv.y, s4.y, c2[r]);
                    c2[r] = fmaf(wv.z, s4.z, c2[r]);
                    c2[r] = fmaf(wv.w, s4.w, c2[r]);
                }
            }
            float m2[8];
#pragma unroll
            for (int r = 0; r < 8; ++r) {
                const float rst2 = ((m1[r] - thr) > 0.f) ? thr : 0.f; // NEW mem1 (ref bug kept)
                m2[r] = fmaf(betac, m1[r], c2[r]) - rst2;
            }
#pragma unroll
            for (int r = 0; r < 8; ++r)
                sw[(b * 8 + r) * 68 + lane] = ((m2[r] - thr) > 0.f) ? 1.f : 0.f;
            asm volatile("s_waitcnt lgkmcnt(0)" ::: "memory");

            // c3 = spk2 @ Wo^T + bo
            float c3[8];
#pragma unroll
            for (int r = 0; r < 8; ++r) c3[r] = bor;
#pragma unroll 4
            for (int ib = 0; ib < 16; ++ib) {
                const float4 wv = *(const float4*)&Wob[ib * 256 + lane * 4];
#pragma unroll
                for (int r = 0; r < 8; ++r) {
                    const float4 s4 = *(const float4*)&sw[(b * 8 + r) * 68 + ib * 4];
                    c3[r] = fmaf(wv.x, s4.x, c3[r]);
                    c3[r] = fmaf(wv.y, s4.y, c3[r]);
                    c3[r] = fmaf(wv.z, s4.z, c3[r]);
                    c3[r] = fmaf(wv.w, s4.w, c3[r]);
                }
            }
            const long rowb = row0 + (long)b * 8;
#pragma unroll
            for (int r = 0; r < 8; ++r) {
                const long rr = rowb + r;
                if (rr < B) {
                    const float m3 = fmaf(betao, m2[r], c3[r]);   // lif_none on NEW mem2
                    out[(size_t)rr * 64 + lane] = tanhf(m3) * 3.14159265358979323846f;
                }
            }
        }
    } else {
        // --------------------------- critic ---------------------------
        const float bv1r = bv1[lane], bv2r = bv2[lane];
        const float* Wv2b = ws + 40960;
        float* outc = out + (size_t)B * 64;

        for (int b = 0; b < 4; ++b) {
            float hreg[8];
#pragma unroll
            for (int r = 0; r < 8; ++r)
                hreg[r] = fmaxf(sw[(b * 8 + r) * 68 + lane] + bv1r, 0.f);
#pragma unroll
            for (int r = 0; r < 8; ++r)
                sw[(b * 8 + r) * 68 + lane] = hreg[r];
            asm volatile("s_waitcnt lgkmcnt(0)" ::: "memory");

            float cv[8];
#pragma unroll
            for (int r = 0; r < 8; ++r) cv[r] = bv2r;
#pragma unroll 4
            for (int ib = 0; ib < 16; ++ib) {
                const float4 wv = *(const float4*)&Wv2b[ib * 256 + lane * 4];
#pragma unroll
                for (int r = 0; r < 8; ++r) {
                    const float4 h4 = *(const float4*)&sw[(b * 8 + r) * 68 + ib * 4];
                    cv[r] = fmaf(wv.x, h4.x, cv[r]);
                    cv[r] = fmaf(wv.y, h4.y, cv[r]);
                    cv[r] = fmaf(wv.z, h4.z, cv[r]);
                    cv[r] = fmaf(wv.w, h4.w, cv[r]);
                }
            }
            const long rowb = row0 + (long)b * 8;
#pragma unroll
            for (int r = 0; r < 8; ++r) {
                const long rr = rowb + r;
                if (rr < B)
                    outc[(size_t)rr * 64 + lane] = fmaxf(cv[r], 0.f);
            }
        }
    }
}

extern "C" void kernel_launch(void* const* d_in, const int* in_sizes, int n_in,
                              void* d_out, int out_size, void* d_ws, size_t ws_size,
                              hipStream_t stream)
{
    const float* x        = (const float*)d_in[0];
    const float* W1       = (const float*)d_in[1];
    const float* b1       = (const float*)d_in[2];
    const float* W2       = (const float*)d_in[3];
    const float* b2       = (const float*)d_in[4];
    const float* Wo       = (const float*)d_in[5];
    const float* bo       = (const float*)d_in[6];
    const float* beta_in  = (const float*)d_in[7];
    const float* thr_in   = (const float*)d_in[8];
    const float* beta_out = (const float*)d_in[9];
    const float* Wv1      = (const float*)d_in[10];
    const float* bv1      = (const float*)d_in[11];
    const float* Wv2      = (const float*)d_in[12];
    const float* bv2      = (const float*)d_in[13];
    float* out = (float*)d_out;
    float* ws  = (float*)d_ws;          // needs 45056 floats = 176 KB

    const int B = in_sizes[0] / 256;

    hipLaunchKernelGGL(prep_weights, dim3(64), dim3(256), 0, stream,
                       W1, Wv1, W2, Wo, Wv2, ws);

    const int nblk = (B + 63) / 64;     // 2048 for B=131072
    hipLaunchKernelGGL(snn_main, dim3(nblk), dim3(BT), 0, stream,
                       x, ws, b1, b2, bo, beta_in, thr_in, beta_out,
                       bv1, bv2, out, B);
}